// Round 2
// baseline (283.793 us; speedup 1.0000x reference)
//
#include <hip/hip_runtime.h>
#include <hip/hip_bf16.h>
#include <stdint.h>

// SymmetricTensorProduct: n=8192, MUL=128, DIM_IN=512
//   out_s[z,u] = (1/16)*xs[z,u]*S[z,u] + (1/(16*sqrt3))*sum_i V_i[z,u]*xv[z,u,i]
//     S = xs @ w_ss^T ; V_i = xv_i @ w_vv^T
//   t[z,v,w]   = sum_u xs[z,u]*w_sv[u,v,w]
//   out_v[z,w,i] = (1/128)*sum_v t[z,v,w]*xv[z,v,i]
//
// Round-2 (diagnostic + forward progress):
//   - out_s: exact fp32 VALU kernel (no MFMA, no prep deps); w_ss/w_vv staged
//     in LDS with +1 padding.
//   - out_v: bf16 MFMA, transposed GEMM C[(v,w)][z] so the v-contraction is a
//     per-lane register accumulation. Single phase per wave (no LDS combine).
//   - workspace use shrunk to 6 MB (xs_bf 2MB + Wt 4MB).

#define NZ 8192
#define NM (8192*128)   // 2^20

typedef __attribute__((ext_vector_type(8))) short bf16x8;
typedef __attribute__((ext_vector_type(4))) float f32x4;

__device__ __forceinline__ ushort f2bf(float f) {
  uint32_t u = __builtin_bit_cast(uint32_t, f);
  u += 0x7fffu + ((u >> 16) & 1u);   // RNE
  return (ushort)(u >> 16);
}

// ---------------- prep: cast xs -> bf16 -------------------------------------
__global__ void prep_cast(const float* __restrict__ x,
                          ushort* __restrict__ xs_bf) {
  int t = blockIdx.x * 256 + threadIdx.x;
  if (t < NM) {
    int z = t >> 7, u = t & 127;
    xs_bf[t] = f2bf(x[(size_t)z * 512 + u]);
  }
}

// ---------------- prep: transpose w_sv[u][v][w] -> Wt[(v,w)][u] (bf16) -----
__global__ void prep_transpose(const float* __restrict__ w_sv,
                               ushort* __restrict__ Wt) {
  __shared__ float tile[32][129];
  int bu = blockIdx.x & 3;            // 4 u-tiles of 32
  int bm = blockIdx.x >> 2;           // 128 m-tiles of 128
  int t = threadIdx.x;
  int u0 = bu * 32, m0 = bm * 128;
  for (int rr = 0; rr < 32; rr += 2) {
    int u = u0 + rr + (t >> 7);
    int m = m0 + (t & 127);
    tile[rr + (t >> 7)][t & 127] = w_sv[(size_t)u * 16384 + m];
  }
  __syncthreads();
  for (int mm = 0; mm < 128; mm += 8) {
    int m = m0 + mm + (t >> 5);
    int ul = t & 31;
    Wt[(size_t)m * 128 + u0 + ul] = f2bf(tile[ul][mm + (t >> 5)]);
  }
}

// ---------------- out_s: exact fp32 VALU ------------------------------------
// 256 blocks x 256 thr; block handles 32 z; thread = (u = t&127, zh = t>>7).
// w_ss/w_vv staged in LDS (+1 pad -> (u+v)%32 banks, 2-way = free).
__global__ __launch_bounds__(256) void outs_valu(
    const float* __restrict__ x, const float* __restrict__ w_ss,
    const float* __restrict__ w_vv, float* __restrict__ out) {
  __shared__ float wss[128][129];
  __shared__ float wvv[128][129];
  int t = threadIdx.x;
  for (int k = t; k < 16384; k += 256) {
    int u = k >> 7, v = k & 127;
    wss[u][v] = w_ss[k];
    wvv[u][v] = w_vv[k];
  }
  __syncthreads();
  int u = t & 127, zh = t >> 7;
  int z0 = blockIdx.x * 32;
  for (int zz = 0; zz < 32; zz += 2) {
    int z = z0 + zz + zh;
    const float* xr = x + (size_t)z * 512;
    float s1 = 0.f, s2 = 0.f, s3 = 0.f, s4 = 0.f;
#pragma unroll 4
    for (int v = 0; v < 128; ++v) {
      float xsv = xr[v];
      float x0 = xr[128 + 3 * v], x1 = xr[129 + 3 * v], x2 = xr[130 + 3 * v];
      s1 += wss[u][v] * xsv;
      float wv = wvv[u][v];
      s2 += wv * x0;
      s3 += wv * x1;
      s4 += wv * x2;
    }
    out[(size_t)z * 512 + u] =
        0.0625f * xr[u] * s1 +
        0.036084391824351615f *
            (s2 * xr[128 + 3 * u] + s3 * xr[129 + 3 * u] + s4 * xr[130 + 3 * u]);
  }
}

// ---------------- out_v (dominant kernel) -----------------------------------
// Grid: 512 blocks = 64 z-blocks(128 z) x 8 w-blocks(16 w).
// Block: 4 waves; wave wid owns 32 z (2 n-tiles) x 16 w x ALL 128 v.
// C[m=(v,w)][n=z]: col(lane&15)=z, row(4*(lane>>4)+reg)=w  [m89/m91 layout]
__global__ __launch_bounds__(256, 2) void outv_kernel(
    const float* __restrict__ x, const ushort* __restrict__ xs_bf,
    const ushort* __restrict__ Wt, float* __restrict__ out) {
  int bid = blockIdx.x;
  int wb = bid & 7, zb = bid >> 3;
  int tid = threadIdx.x;
  int wid = tid >> 6, l = tid & 63;
  int lr = l & 15, lg = l >> 4;
  int z0 = zb * 128 + wid * 32;
  int w0 = wb * 16;

  // B-fragments: xs for 2 z-tiles x 4 k-chunks, held in registers all kernel.
  bf16x8 b[2][4];
  for (int n = 0; n < 2; ++n)
    for (int kk = 0; kk < 4; ++kk)
      b[n][kk] = *(const bf16x8*)(xs_bf + (size_t)(z0 + n * 16 + lr) * 128 + kk * 32 + lg * 8);

  float acc[2][4][3] = {};   // [n-tile][reg(w)][i]

  for (int v = 0; v < 128; ++v) {
    const ushort* arow = Wt + (size_t)(v * 128 + w0 + lr) * 128 + lg * 8;
    bf16x8 a0 = *(const bf16x8*)(arow);
    bf16x8 a1 = *(const bf16x8*)(arow + 32);
    bf16x8 a2 = *(const bf16x8*)(arow + 64);
    bf16x8 a3 = *(const bf16x8*)(arow + 96);
#pragma unroll
    for (int n = 0; n < 2; ++n) {
      f32x4 t = {0.f, 0.f, 0.f, 0.f};
      t = __builtin_amdgcn_mfma_f32_16x16x32_bf16(a0, b[n][0], t, 0, 0, 0);
      t = __builtin_amdgcn_mfma_f32_16x16x32_bf16(a1, b[n][1], t, 0, 0, 0);
      t = __builtin_amdgcn_mfma_f32_16x16x32_bf16(a2, b[n][2], t, 0, 0, 0);
      t = __builtin_amdgcn_mfma_f32_16x16x32_bf16(a3, b[n][3], t, 0, 0, 0);
      int z = z0 + n * 16 + lr;
      const float* xv = x + (size_t)z * 512 + 128 + 3 * v;
      float x0 = xv[0], x1 = xv[1], x2 = xv[2];
#pragma unroll
      for (int r = 0; r < 4; ++r) {
        acc[n][r][0] += t[r] * x0;
        acc[n][r][1] += t[r] * x1;
        acc[n][r][2] += t[r] * x2;
      }
    }
  }

#pragma unroll
  for (int n = 0; n < 2; ++n) {
    for (int r = 0; r < 4; ++r) {
      int z = z0 + n * 16 + lr;
      int w = w0 + lg * 4 + r;
      float* o = out + (size_t)z * 512 + 128 + 3 * w;
      o[0] = acc[n][r][0] * 0.0078125f;
      o[1] = acc[n][r][1] * 0.0078125f;
      o[2] = acc[n][r][2] * 0.0078125f;
    }
  }
}

// ---------------- launch ----------------------------------------------------
extern "C" void kernel_launch(void* const* d_in, const int* in_sizes, int n_in,
                              void* d_out, int out_size, void* d_ws, size_t ws_size,
                              hipStream_t stream) {
  const float* x    = (const float*)d_in[0];
  const float* w_ss = (const float*)d_in[1];
  const float* w_sv = (const float*)d_in[2];
  const float* w_vv = (const float*)d_in[3];
  float* out = (float*)d_out;

  char* ws = (char*)d_ws;
  ushort* xs_bf = (ushort*)ws;                                  // 2 MB
  ushort* Wt    = (ushort*)(ws + (size_t)2 * 1024 * 1024);      // 4 MB

  prep_cast<<<NM / 256, 256, 0, stream>>>(x, xs_bf);
  prep_transpose<<<512, 256, 0, stream>>>(w_sv, Wt);
  outs_valu<<<256, 256, 0, stream>>>(x, w_ss, w_vv, out);
  outv_kernel<<<512, 256, 0, stream>>>(x, xs_bf, Wt, out);
}

// Round 3
// 273.500 us; speedup vs baseline: 1.0376x; 1.0376x over previous
//
#include <hip/hip_runtime.h>
#include <hip/hip_bf16.h>
#include <stdint.h>

// SymmetricTensorProduct: n=8192, MUL=128, DIM_IN=512
//   out_s[z,u] = (1/16)*xs[z,u]*S[z,u] + (1/(16*sqrt3))*sum_i V_i[z,u]*xv[z,u,i]
//     S = xs @ w_ss^T ; V_i = xv_i @ w_vv^T
//   t[z,v,w]   = sum_u xs[z,u]*w_sv[u,v,w]
//   out_v[z,w,i] = (1/128)*sum_v t[z,v,w]*xv[z,v,i]
//
// Round-3: occupancy + latency attack on outv (1024 blocks, A-prefetch,
// xv staged in LDS), and out_s moved to MFMA with the round-2-verified
// operand convention: mfma(a,b,c) -> out[reg 4*lg+r = row of a][lane&15 = row of b],
// both operands loaded as [row = lane&15][k = kk*32 + (lane>>4)*8 + j].

#define NZ 8192
#define NM (8192*128)   // 2^20

typedef __attribute__((ext_vector_type(8))) short bf16x8;
typedef __attribute__((ext_vector_type(4))) float f32x4;

__device__ __forceinline__ ushort f2bf(float f) {
  uint32_t u = __builtin_bit_cast(uint32_t, f);
  u += 0x7fffu + ((u >> 16) & 1u);   // RNE
  return (ushort)(u >> 16);
}
__device__ __forceinline__ float bf2f(ushort u) {
  uint32_t v = ((uint32_t)u) << 16;
  return __builtin_bit_cast(float, v);
}

// ---------------- prep: cast xs, w_ss, w_vv -> bf16 -------------------------
__global__ void prep_cast(const float* __restrict__ x,
                          const float* __restrict__ w_ss,
                          const float* __restrict__ w_vv,
                          ushort* __restrict__ xs_bf,
                          ushort* __restrict__ wssb,
                          ushort* __restrict__ wvvb) {
  int t = blockIdx.x * 256 + threadIdx.x;
  if (t < NM) {
    int z = t >> 7, u = t & 127;
    xs_bf[t] = f2bf(x[(size_t)z * 512 + u]);
  } else if (t < NM + 16384) {
    int k = t - NM;
    wssb[k] = f2bf(w_ss[k]);
  } else if (t < NM + 32768) {
    int k = t - NM - 16384;
    wvvb[k] = f2bf(w_vv[k]);
  }
}

// ---------------- prep: transpose w_sv[u][v][w] -> Wt[(v,w)][u] (bf16) -----
__global__ void prep_transpose(const float* __restrict__ w_sv,
                               ushort* __restrict__ Wt) {
  __shared__ float tile[32][129];
  int bu = blockIdx.x & 3;            // 4 u-tiles of 32
  int bm = blockIdx.x >> 2;           // 128 m-tiles of 128
  int t = threadIdx.x;
  int u0 = bu * 32, m0 = bm * 128;
  for (int rr = 0; rr < 32; rr += 2) {
    int u = u0 + rr + (t >> 7);
    int m = m0 + (t & 127);
    tile[rr + (t >> 7)][t & 127] = w_sv[(size_t)u * 16384 + m];
  }
  __syncthreads();
  for (int mm = 0; mm < 128; mm += 8) {
    int m = m0 + mm + (t >> 5);
    int ul = t & 31;
    Wt[(size_t)m * 128 + u0 + ul] = f2bf(tile[ul][mm + (t >> 5)]);
  }
}

// ---------------- out_s via MFMA --------------------------------------------
// Grid 1024 = 128 z-blocks(64 z) x 8 u-tiles(16 u); block = 4 waves, wave = 16z.
// a = weight rows (u via lr on load), b = xs/xv rows (z via lr), out u=u0+4lg+r, z=z0+lr.
__global__ __launch_bounds__(256) void outs_mfma(
    const float* __restrict__ x, const ushort* __restrict__ xs_bf,
    const ushort* __restrict__ wssb, const ushort* __restrict__ wvvb,
    float* __restrict__ out) {
  int bid = blockIdx.x;
  int ub = bid & 7, zb = bid >> 3;
  int tid = threadIdx.x, wid = tid >> 6, l = tid & 63;
  int lr = l & 15, lg = l >> 4;
  int z0 = zb * 64 + wid * 16, u0 = ub * 16;
  int z = z0 + lr;
  const float* xrow = x + (size_t)z * 512;

  f32x4 css = {0.f, 0.f, 0.f, 0.f};
  f32x4 cv0 = {0.f, 0.f, 0.f, 0.f};
  f32x4 cv1 = {0.f, 0.f, 0.f, 0.f};
  f32x4 cv2 = {0.f, 0.f, 0.f, 0.f};

#pragma unroll
  for (int kk = 0; kk < 4; ++kk) {
    int k0 = kk * 32 + lg * 8;
    bf16x8 as = *(const bf16x8*)(wssb + (size_t)(u0 + lr) * 128 + k0);
    bf16x8 av = *(const bf16x8*)(wvvb + (size_t)(u0 + lr) * 128 + k0);
    bf16x8 bs = *(const bf16x8*)(xs_bf + (size_t)z * 128 + k0);
    // xv B-fragments: 24 contiguous floats x[z*512+128+3*k0 ..] = v in [k0,k0+8) x i
    float4 f[6];
    const float4* src = (const float4*)(xrow + 128 + 3 * k0);
#pragma unroll
    for (int q = 0; q < 6; ++q) f[q] = src[q];
    const float* ff = (const float*)f;
    bf16x8 b0, b1, b2;
#pragma unroll
    for (int j = 0; j < 8; ++j) {
      b0[j] = (short)f2bf(ff[3 * j + 0]);
      b1[j] = (short)f2bf(ff[3 * j + 1]);
      b2[j] = (short)f2bf(ff[3 * j + 2]);
    }
    css = __builtin_amdgcn_mfma_f32_16x16x32_bf16(as, bs, css, 0, 0, 0);
    cv0 = __builtin_amdgcn_mfma_f32_16x16x32_bf16(av, b0, cv0, 0, 0, 0);
    cv1 = __builtin_amdgcn_mfma_f32_16x16x32_bf16(av, b1, cv1, 0, 0, 0);
    cv2 = __builtin_amdgcn_mfma_f32_16x16x32_bf16(av, b2, cv2, 0, 0, 0);
  }

#pragma unroll
  for (int r = 0; r < 4; ++r) {
    int u = u0 + lg * 4 + r;
    float xsv = xrow[u];
    const float* xvu = xrow + 128 + 3 * u;
    out[(size_t)z * 512 + u] =
        0.0625f * xsv * css[r] +
        0.036084391824351615f * (cv0[r] * xvu[0] + cv1[r] * xvu[1] + cv2[r] * xvu[2]);
  }
}

// ---------------- out_v (dominant kernel) -----------------------------------
// Grid: 1024 blocks = 256 z-blocks(32 z) x 4 w-blocks(32 w).
// Block: 4 waves = 2 z-tiles(16 z) x 2 w-tiles(16 w); each wave all 128 v.
// A rows prefetched (reg double-buffer); xv staged in LDS bf16 planes.
__global__ __launch_bounds__(256) void outv_kernel(
    const float* __restrict__ x, const ushort* __restrict__ xs_bf,
    const ushort* __restrict__ Wt, float* __restrict__ out) {
  __shared__ ushort xv_lds[12672];   // [v]*99 + [i]*33 + [zloc], 32 z per block
  int bid = blockIdx.x;
  int wb = bid & 3, zb = bid >> 2;
  int tid = threadIdx.x;
  int wid = tid >> 6, l = tid & 63;
  int zt = wid & 1, wt = wid >> 1;
  int lr = l & 15, lg = l >> 4;
  int z0 = zb * 32 + zt * 16;
  int w0 = wb * 32 + wt * 16;
  int zloc = zt * 16 + lr;

  // stage xv tile: 32 z x 384 c, coalesced read, ~2-way-conflict LDS write
  for (int k = tid; k < 12288; k += 256) {
    int zs = k / 384, c = k - zs * 384;
    xv_lds[33 * c + zs] = f2bf(x[(size_t)(zb * 32 + zs) * 512 + 128 + c]);
  }

  // B-fragments: xs for this wave's 16 z, 4 k-chunks (held all kernel)
  bf16x8 b[4];
#pragma unroll
  for (int kk = 0; kk < 4; ++kk)
    b[kk] = *(const bf16x8*)(xs_bf + (size_t)(z0 + lr) * 128 + kk * 32 + lg * 8);

  __syncthreads();

  const ushort* Ap = Wt + (size_t)(w0 + lr) * 128 + lg * 8;  // + v*16384
  bf16x8 a0 = *(const bf16x8*)(Ap);
  bf16x8 a1 = *(const bf16x8*)(Ap + 32);
  bf16x8 a2 = *(const bf16x8*)(Ap + 64);
  bf16x8 a3 = *(const bf16x8*)(Ap + 96);

  float acc[4][3] = {};   // [reg(w)][i]

  for (int v = 0; v < 128; ++v) {
    bf16x8 c0 = a0, c1 = a1, c2 = a2, c3 = a3;
    // prefetch v+1 (clamped; unconditional to keep the pipeline branch-free)
    const ushort* p = Ap + (size_t)(v < 127 ? v + 1 : 127) * 16384;
    a0 = *(const bf16x8*)(p);
    a1 = *(const bf16x8*)(p + 32);
    a2 = *(const bf16x8*)(p + 64);
    a3 = *(const bf16x8*)(p + 96);

    int e = 99 * v + zloc;
    ushort u0v = xv_lds[e];
    ushort u1v = xv_lds[e + 33];
    ushort u2v = xv_lds[e + 66];

    f32x4 t = {0.f, 0.f, 0.f, 0.f};
    t = __builtin_amdgcn_mfma_f32_16x16x32_bf16(c0, b[0], t, 0, 0, 0);
    t = __builtin_amdgcn_mfma_f32_16x16x32_bf16(c1, b[1], t, 0, 0, 0);
    t = __builtin_amdgcn_mfma_f32_16x16x32_bf16(c2, b[2], t, 0, 0, 0);
    t = __builtin_amdgcn_mfma_f32_16x16x32_bf16(c3, b[3], t, 0, 0, 0);

    float x0 = bf2f(u0v), x1 = bf2f(u1v), x2 = bf2f(u2v);
#pragma unroll
    for (int r = 0; r < 4; ++r) {
      acc[r][0] += t[r] * x0;
      acc[r][1] += t[r] * x1;
      acc[r][2] += t[r] * x2;
    }
  }

#pragma unroll
  for (int r = 0; r < 4; ++r) {
    int z = z0 + lr;
    int w = w0 + lg * 4 + r;
    float* o = out + (size_t)z * 512 + 128 + 3 * w;
    o[0] = acc[r][0] * 0.0078125f;
    o[1] = acc[r][1] * 0.0078125f;
    o[2] = acc[r][2] * 0.0078125f;
  }
}

// ---------------- launch ----------------------------------------------------
extern "C" void kernel_launch(void* const* d_in, const int* in_sizes, int n_in,
                              void* d_out, int out_size, void* d_ws, size_t ws_size,
                              hipStream_t stream) {
  const float* x    = (const float*)d_in[0];
  const float* w_ss = (const float*)d_in[1];
  const float* w_sv = (const float*)d_in[2];
  const float* w_vv = (const float*)d_in[3];
  float* out = (float*)d_out;

  char* ws = (char*)d_ws;
  ushort* xs_bf = (ushort*)ws;                                  // 2 MB
  ushort* Wt    = (ushort*)(ws + (size_t)2 * 1024 * 1024);      // 4 MB
  ushort* wssb  = (ushort*)(ws + (size_t)6 * 1024 * 1024);      // 32 KB
  ushort* wvvb  = (ushort*)(ws + (size_t)6 * 1024 * 1024 + 32768);

  prep_cast<<<(NM + 32768) / 256, 256, 0, stream>>>(x, w_ss, w_vv, xs_bf, wssb, wvvb);
  prep_transpose<<<512, 256, 0, stream>>>(w_sv, Wt);
  outs_mfma<<<1024, 256, 0, stream>>>(x, xs_bf, wssb, wvvb, out);
  outv_kernel<<<1024, 256, 0, stream>>>(x, xs_bf, Wt, out);
}

// Round 4
// 117.870 us; speedup vs baseline: 2.4077x; 2.3203x over previous
//
#include <hip/hip_runtime.h>
#include <hip/hip_bf16.h>
#include <stdint.h>

// SymmetricTensorProduct: n=8192, MUL=128, DIM_IN=512
//   out_s[z,u] = (1/16)*xs[z,u]*S[z,u] + (1/(16*sqrt3))*sum_i V_i[z,u]*xv[z,u,i]
//   t[z,v,w]   = sum_u xs[z,u]*w_sv[u,v,w]
//   out_v[z,w,i] = (1/128)*sum_v t[z,v,w]*xv[z,v,i]
//
// Round-4: outv restructured for A-reuse. Block = 64z x 32w x all 128v;
// per-v 8KB A-tile staged once per block via global_load_lds (dbuf), shared
// by 4 waves; Wt pre-swizzled (k ^= (m&7)<<3) so linear staging + swizzled
// ds_read_b128 is bank-conflict-free; w-chunk in low blockIdx bits pins each
// XCD to a 1MB L2-resident Wt slice. xv from bf16 plane xvp[i][v][z],
// register-prefetched. No atomics, no cross-block reduction.

#define NZ 8192
#define NM (8192*128)   // 2^20

typedef __attribute__((ext_vector_type(8))) short bf16x8;
typedef __attribute__((ext_vector_type(4))) float f32x4;

__device__ __forceinline__ ushort f2bf(float f) {
  uint32_t u = __builtin_bit_cast(uint32_t, f);
  u += 0x7fffu + ((u >> 16) & 1u);   // RNE
  return (ushort)(u >> 16);
}
__device__ __forceinline__ float bf2f(ushort u) {
  uint32_t v = ((uint32_t)u) << 16;
  return __builtin_bit_cast(float, v);
}
__device__ __forceinline__ void gload16(const void* g, void* l) {
  __builtin_amdgcn_global_load_lds((const __attribute__((address_space(1))) void*)g,
                                   (__attribute__((address_space(3))) void*)l, 16, 0, 0);
}

// ---------------- prep: casts (xs, xvp planes, w_ss, w_vv) ------------------
__global__ void prep_cast(const float* __restrict__ x,
                          const float* __restrict__ w_ss,
                          const float* __restrict__ w_vv,
                          ushort* __restrict__ xs_bf,
                          ushort* __restrict__ xvp,
                          ushort* __restrict__ wssb,
                          ushort* __restrict__ wvvb) {
  int t = blockIdx.x * 256 + threadIdx.x;
  if (t < NM) {
    int z = t >> 7, u = t & 127;
    xs_bf[t] = f2bf(x[(size_t)z * 512 + u]);
  } else if (t < 4 * NM) {            // xvp[i][v][z], write-coalesced on z
    int p = t - NM;
    int i = p >> 20;
    int r = p & (NM - 1);
    int v = r >> 13, z = r & 8191;
    xvp[p] = f2bf(x[(size_t)z * 512 + 128 + 3 * v + i]);
  } else if (t < 4 * NM + 16384) {
    int k = t - 4 * NM;
    wssb[k] = f2bf(w_ss[k]);
  } else if (t < 4 * NM + 32768) {
    int k = t - 4 * NM - 16384;
    wvvb[k] = f2bf(w_vv[k]);
  }
}

// ---- prep: transpose w_sv[u][v][w] -> Wt_sw[(v,w)][k^((m&7)<<3)] (bf16) ----
__global__ void prep_transpose(const float* __restrict__ w_sv,
                               ushort* __restrict__ Wt) {
  __shared__ float tile[32][129];
  int bu = blockIdx.x & 3;            // 4 u-tiles of 32
  int bm = blockIdx.x >> 2;           // 128 m-tiles of 128
  int t = threadIdx.x;
  int u0 = bu * 32, m0 = bm * 128;
  for (int rr = 0; rr < 32; rr += 2) {
    int u = u0 + rr + (t >> 7);
    int m = m0 + (t & 127);
    tile[rr + (t >> 7)][t & 127] = w_sv[(size_t)u * 16384 + m];
  }
  __syncthreads();
  for (int mm = 0; mm < 128; mm += 8) {
    int m = m0 + mm + (t >> 5);
    int k = u0 + (t & 31);
    Wt[(size_t)m * 128 + (k ^ ((m & 7) << 3))] = f2bf(tile[t & 31][mm + (t >> 5)]);
  }
}

// ---------------- out_s via MFMA --------------------------------------------
__global__ __launch_bounds__(256) void outs_mfma(
    const float* __restrict__ x, const ushort* __restrict__ xs_bf,
    const ushort* __restrict__ wssb, const ushort* __restrict__ wvvb,
    float* __restrict__ out) {
  int bid = blockIdx.x;
  int ub = bid & 7, zb = bid >> 3;
  int tid = threadIdx.x, wid = tid >> 6, l = tid & 63;
  int lr = l & 15, lg = l >> 4;
  int z0 = zb * 64 + wid * 16, u0 = ub * 16;
  int z = z0 + lr;
  const float* xrow = x + (size_t)z * 512;

  f32x4 css = {0.f, 0.f, 0.f, 0.f};
  f32x4 cv0 = {0.f, 0.f, 0.f, 0.f};
  f32x4 cv1 = {0.f, 0.f, 0.f, 0.f};
  f32x4 cv2 = {0.f, 0.f, 0.f, 0.f};

#pragma unroll
  for (int kk = 0; kk < 4; ++kk) {
    int k0 = kk * 32 + lg * 8;
    bf16x8 as = *(const bf16x8*)(wssb + (size_t)(u0 + lr) * 128 + k0);
    bf16x8 av = *(const bf16x8*)(wvvb + (size_t)(u0 + lr) * 128 + k0);
    bf16x8 bs = *(const bf16x8*)(xs_bf + (size_t)z * 128 + k0);
    float4 f[6];
    const float4* src = (const float4*)(xrow + 128 + 3 * k0);
#pragma unroll
    for (int q = 0; q < 6; ++q) f[q] = src[q];
    const float* ff = (const float*)f;
    bf16x8 b0, b1, b2;
#pragma unroll
    for (int j = 0; j < 8; ++j) {
      b0[j] = (short)f2bf(ff[3 * j + 0]);
      b1[j] = (short)f2bf(ff[3 * j + 1]);
      b2[j] = (short)f2bf(ff[3 * j + 2]);
    }
    css = __builtin_amdgcn_mfma_f32_16x16x32_bf16(as, bs, css, 0, 0, 0);
    cv0 = __builtin_amdgcn_mfma_f32_16x16x32_bf16(av, b0, cv0, 0, 0, 0);
    cv1 = __builtin_amdgcn_mfma_f32_16x16x32_bf16(av, b1, cv1, 0, 0, 0);
    cv2 = __builtin_amdgcn_mfma_f32_16x16x32_bf16(av, b2, cv2, 0, 0, 0);
  }

#pragma unroll
  for (int r = 0; r < 4; ++r) {
    int u = u0 + lg * 4 + r;
    float xsv = xrow[u];
    const float* xvu = xrow + 128 + 3 * u;
    out[(size_t)z * 512 + u] =
        0.0625f * xsv * css[r] +
        0.036084391824351615f * (cv0[r] * xvu[0] + cv1[r] * xvu[1] + cv2[r] * xvu[2]);
  }
}

// ---------------- out_v (dominant kernel) -----------------------------------
// Grid: 512 = 128 z-blocks(64 z) x 4 w-chunks(32 w); wc = bid&3 -> per-XCD
// Wt working set = 1MB (L2-resident). Block: 4 waves = 2 z-groups(32z=2 n-tiles)
// x 2 w-groups(16w). Per v: 8KB A staged to LDS dbuf, 8 MFMA + 24 FMA per wave.
__global__ __launch_bounds__(256) void outv_kernel(
    const ushort* __restrict__ xs_bf, const ushort* __restrict__ xvp,
    const ushort* __restrict__ Wt, float* __restrict__ out) {
  __shared__ ushort abuf[2][4096];   // 2 x 8KB: 32 rows x 128 k (swizzled bytes)
  int bid = blockIdx.x;
  int wc = bid & 3, zb = bid >> 2;
  int tid = threadIdx.x, wid = tid >> 6, l = tid & 63;
  int wg = wid & 1, zg = wid >> 1;
  int lr = l & 15, lg = l >> 4;
  int z0 = zb * 64, w0 = wc * 32;
  int zA = z0 + zg * 32 + lr;        // z for n=0 (n adds 16)

  // B-fragments (xs), held all kernel: 2 n-tiles x 4 k-chunks
  bf16x8 b[2][4];
#pragma unroll
  for (int n = 0; n < 2; ++n)
#pragma unroll
    for (int kk = 0; kk < 4; ++kk)
      b[n][kk] = *(const bf16x8*)(xs_bf + (size_t)(zA + n * 16) * 128 + kk * 32 + lg * 8);

  // prologue: stage A(v=0), prefetch xv(v=0)
  {
    const ushort* src = Wt + ((size_t)0 * 128 + w0) * 128;
    gload16(src + wid * 1024 + l * 8,       &abuf[0][wid * 1024]);
    gload16(src + wid * 1024 + 512 + l * 8, &abuf[0][wid * 1024 + 512]);
  }
  ushort xc0 = xvp[0 * NM + 0 * 8192 + zA],      xc1 = xvp[0 * NM + 0 * 8192 + zA + 16];
  ushort xc2 = xvp[1 * NM + 0 * 8192 + zA],      xc3 = xvp[1 * NM + 0 * 8192 + zA + 16];
  ushort xc4 = xvp[2 * NM + 0 * 8192 + zA],      xc5 = xvp[2 * NM + 0 * 8192 + zA + 16];
  __syncthreads();

  float acc[2][4][3] = {};   // [n-tile][reg(w)][i]
  int row = wg * 16 + lr;
  int sw = (lr & 7) << 3;

  for (int v = 0; v < 128; ++v) {
    int cb = v & 1;
    ushort xn0, xn1, xn2, xn3, xn4, xn5;
    if (v < 127) {
      const ushort* src = Wt + ((size_t)(v + 1) * 128 + w0) * 128;
      gload16(src + wid * 1024 + l * 8,       &abuf[cb ^ 1][wid * 1024]);
      gload16(src + wid * 1024 + 512 + l * 8, &abuf[cb ^ 1][wid * 1024 + 512]);
      const ushort* xvv = xvp + (size_t)(v + 1) * 8192 + zA;
      xn0 = xvv[0];            xn1 = xvv[16];
      xn2 = xvv[NM];           xn3 = xvv[NM + 16];
      xn4 = xvv[2 * NM];       xn5 = xvv[2 * NM + 16];
    }

    // A-fragments from LDS (swizzled read)
    const ushort* ab = &abuf[cb][row * 128];
    bf16x8 a0 = *(const bf16x8*)(ab + ((0 * 32 + lg * 8) ^ sw));
    bf16x8 a1 = *(const bf16x8*)(ab + ((1 * 32 + lg * 8) ^ sw));
    bf16x8 a2 = *(const bf16x8*)(ab + ((2 * 32 + lg * 8) ^ sw));
    bf16x8 a3 = *(const bf16x8*)(ab + ((3 * 32 + lg * 8) ^ sw));

#pragma unroll
    for (int n = 0; n < 2; ++n) {
      f32x4 t = {0.f, 0.f, 0.f, 0.f};
      t = __builtin_amdgcn_mfma_f32_16x16x32_bf16(a0, b[n][0], t, 0, 0, 0);
      t = __builtin_amdgcn_mfma_f32_16x16x32_bf16(a1, b[n][1], t, 0, 0, 0);
      t = __builtin_amdgcn_mfma_f32_16x16x32_bf16(a2, b[n][2], t, 0, 0, 0);
      t = __builtin_amdgcn_mfma_f32_16x16x32_bf16(a3, b[n][3], t, 0, 0, 0);
      float x0 = bf2f(n == 0 ? xc0 : xc1);
      float x1 = bf2f(n == 0 ? xc2 : xc3);
      float x2 = bf2f(n == 0 ? xc4 : xc5);
#pragma unroll
      for (int r = 0; r < 4; ++r) {
        acc[n][r][0] += t[r] * x0;
        acc[n][r][1] += t[r] * x1;
        acc[n][r][2] += t[r] * x2;
      }
    }
    xc0 = xn0; xc1 = xn1; xc2 = xn2; xc3 = xn3; xc4 = xn4; xc5 = xn5;
    __syncthreads();
  }

#pragma unroll
  for (int n = 0; n < 2; ++n) {
#pragma unroll
    for (int r = 0; r < 4; ++r) {
      int z = zA + n * 16;
      int w = w0 + wg * 16 + lg * 4 + r;
      float* o = out + (size_t)z * 512 + 128 + 3 * w;
      o[0] = acc[n][r][0] * 0.0078125f;
      o[1] = acc[n][r][1] * 0.0078125f;
      o[2] = acc[n][r][2] * 0.0078125f;
    }
  }
}

// ---------------- launch ----------------------------------------------------
extern "C" void kernel_launch(void* const* d_in, const int* in_sizes, int n_in,
                              void* d_out, int out_size, void* d_ws, size_t ws_size,
                              hipStream_t stream) {
  const float* x    = (const float*)d_in[0];
  const float* w_ss = (const float*)d_in[1];
  const float* w_sv = (const float*)d_in[2];
  const float* w_vv = (const float*)d_in[3];
  float* out = (float*)d_out;

  char* ws = (char*)d_ws;
  ushort* xs_bf = (ushort*)ws;                                  // 2 MB
  ushort* Wt    = (ushort*)(ws + (size_t)2 * 1024 * 1024);      // 4 MB (swizzled)
  ushort* xvp   = (ushort*)(ws + (size_t)6 * 1024 * 1024);      // 6 MB
  ushort* wssb  = (ushort*)(ws + (size_t)12 * 1024 * 1024);     // 32 KB
  ushort* wvvb  = (ushort*)(ws + (size_t)12 * 1024 * 1024 + 32768);

  prep_cast<<<(4 * NM + 32768) / 256, 256, 0, stream>>>(x, w_ss, w_vv,
                                                        xs_bf, xvp, wssb, wvvb);
  prep_transpose<<<512, 256, 0, stream>>>(w_sv, Wt);
  outs_mfma<<<1024, 256, 0, stream>>>(x, xs_bf, wssb, wvvb, out);
  outv_kernel<<<512, 256, 0, stream>>>(xs_bf, xvp, Wt, out);
}